// Round 14
// baseline (876.928 us; speedup 1.0000x reference)
//
#include <hip/hip_runtime.h>
#include <hip/hip_fp16.h>
#include <math.h>

#define NN 20000
#define NE 320000
#define NG 16
#define ECAP 48   // edges staged per batch in k_gather (deg ~16+-4, max ~40)

typedef _Float16 f16x2 __attribute__((ext_vector_type(2)));
typedef _Float16 f16x8 __attribute__((ext_vector_type(8)));
typedef float    f32x4 __attribute__((ext_vector_type(4)));

__device__ __forceinline__ float dot2f(f16x2 a, f16x2 b, float c){
#if defined(__has_builtin)
#if __has_builtin(__builtin_amdgcn_fdot2)
  return __builtin_amdgcn_fdot2(a, b, c, false);
#else
  return c + (float)a.x*(float)b.x + (float)a.y*(float)b.y;
#endif
#else
  return c + (float)a.x*(float)b.x + (float)a.y*(float)b.y;
#endif
}

__device__ __forceinline__ f16x2 pack2f(float a, float b){
  f16x2 r; r.x = (_Float16)a; r.y = (_Float16)b; return r;
}

__device__ __forceinline__ float silu_f(float x){ return x / (1.0f + __expf(-x)); }

// recompute bessel basis from dR (identical math/constants throughout all rounds)
__device__ __forceinline__ void bessel8(const float* __restrict__ dR, int e, float* rb){
  float x = dR[3*e+0], y = dR[3*e+1], z = dR[3*e+2];
  float r = sqrtf(x*x + y*y + z*z);
  float rs = fmaxf(r, 1e-6f);
  float inv = 1.0f / rs;
  float env;
  if (r < 3.5f) env = 1.0f;
  else if (r > 4.0f) env = 0.0f;
  else {
    float t = (r - 3.5f) * 2.0f;
    env = 0.5f * (cosf(3.14159265358979323846f * t) + 1.0f);
  }
  float c = 0.7071067811865476f * inv * env;
  #pragma unroll
  for (int k=0;k<8;k++){
    float arg = (float)(k+1) * 0.7853981633974483f * rs;
    rb[k] = c * sinf(arg);
  }
}

// ---------------- geometry: spherical harmonics only ----------------
__global__ void k_geom(const float* __restrict__ dR, float* __restrict__ sh1){
  int e = blockIdx.x*256 + threadIdx.x;
  if (e >= NE) return;
  float x = dR[3*e+0], y = dR[3*e+1], z = dR[3*e+2];
  float r = sqrtf(x*x + y*y + z*z);
  float inv = 1.0f / fmaxf(r, 1e-6f);
  const float SQ3 = 1.7320508075688772f;
  sh1[3*e+0] = SQ3 * x * inv;
  sh1[3*e+1] = SQ3 * y * inv;
  sh1[3*e+2] = SQ3 * z * inv;
}

// ---------------- node embedding ----------------
__global__ void k_embed(const float* __restrict__ nodes, const float* __restrict__ W,
                        float* __restrict__ s){
  int idx = blockIdx.x*256 + threadIdx.x;   // N*64 exact
  int n = idx>>6, o = idx&63;
  float a = nodes[n*4+0]*W[o] + nodes[n*4+1]*W[64+o]
          + nodes[n*4+2]*W[128+o] + nodes[n*4+3]*W[192+o];
  s[idx] = 0.5f*a;
}

// ---------------- counting sort of edges by receiver ----------------
__global__ void k_hist(const int* __restrict__ receivers, int* __restrict__ cnt){
  int e = blockIdx.x*256 + threadIdx.x;
  if (e < NE) atomicAdd(&cnt[receivers[e]], 1);
}

__global__ void k_scan(const int* __restrict__ cnt, int* __restrict__ row, int* __restrict__ cur){
  __shared__ int lsum[1024];
  int t = threadIdx.x;
  int base = t*20;
  int local[20];
  int s = 0;
  #pragma unroll
  for (int i=0;i<20;i++){
    int idx = base+i;
    int v = (idx<NN) ? cnt[idx] : 0;
    local[i] = s; s += v;
  }
  lsum[t] = s; __syncthreads();
  for (int off=1; off<1024; off<<=1){
    int v = (t>=off) ? lsum[t-off] : 0;
    __syncthreads();
    lsum[t] += v;
    __syncthreads();
  }
  int pre = (t>0) ? lsum[t-1] : 0;
  #pragma unroll
  for (int i=0;i<20;i++){
    int idx = base+i;
    if (idx<NN){ int r = pre+local[i]; row[idx]=r; cur[idx]=r; }
  }
  if (t==1023) row[NN] = lsum[1023];
}

__global__ void k_scatter(const int* __restrict__ receivers, int* __restrict__ cur,
                          int* __restrict__ perm){
  int e = blockIdx.x*256 + threadIdx.x;
  if (e < NE){
    int d = receivers[e];
    int p = atomicAdd(&cur[d], 1);
    perm[p] = e;
  }
}

// ---------------- per-layer node linears: 16 nodes/block, 4 nodes/wave ----------------
__global__ void k_node(const float* __restrict__ s, const float* __restrict__ v,
                       const float* __restrict__ attrs,
                       const float* __restrict__ W1s, const float* __restrict__ W1v,
                       const float* __restrict__ Wscs, const float* __restrict__ Wscv,
                       __half* __restrict__ s1, __half* __restrict__ v1,
                       float* __restrict__ scs, float* __restrict__ scv){
  __shared__ float ls[16][64];
  __shared__ float lv[16][96];
  __shared__ float la[16][4];
  int tid = threadIdx.x;
  int nb = blockIdx.x*16;   // 1250*16 = 20000 exact
  for (int i=tid;i<1024;i+=256) ls[i>>6][i&63] = s[(size_t)(nb+(i>>6))*64 + (i&63)];
  for (int i=tid;i<1536;i+=256){ int j=i/96, q=i-96*j; lv[j][q] = v[(size_t)(nb+j)*96+q]; }
  if (tid<64) la[tid>>2][tid&3] = attrs[(nb+(tid>>2))*4 + (tid&3)];
  __syncthreads();
  int w = tid>>6, q = tid&63;
  int jb = w*4;                       // this wave's 4 nodes: nb+jb .. nb+jb+3
  float laj[4][4];
  #pragma unroll
  for (int j=0;j<4;j++)
    #pragma unroll
    for (int e=0;e<4;e++) laj[j][e] = la[jb+j][e];

  // s1 = s @ W1s / 8
  {
    float acc[4] = {0,0,0,0};
    for (int i=0;i<64;i++){
      float wv = W1s[i*64+q];
      #pragma unroll
      for (int j=0;j<4;j++) acc[j] = fmaf(ls[jb+j][i], wv, acc[j]);
    }
    #pragma unroll
    for (int j=0;j<4;j++) s1[(size_t)(nb+jb+j)*64+q] = __float2half(acc[j]*0.125f);
  }
  // sc_s
  #pragma unroll 1
  for (int o=q;o<96;o+=64){
    float acc[4] = {0,0,0,0};
    for (int i=0;i<64;i++){
      const float* wp = Wscs + (i*4)*96 + o;
      float w0=wp[0], w1=wp[96], w2=wp[192], w3=wp[288];
      #pragma unroll
      for (int j=0;j<4;j++){
        float fold = laj[j][0]*w0 + laj[j][1]*w1 + laj[j][2]*w2 + laj[j][3]*w3;
        acc[j] = fmaf(ls[jb+j][i], fold, acc[j]);
      }
    }
    #pragma unroll
    for (int j=0;j<4;j++) scs[(size_t)(nb+jb+j)*96+o] = acc[j]*0.0625f;
  }
  // v1
  #pragma unroll 1
  for (int f=q;f<96;f+=64){
    int op=f/3, c=f-3*op;
    float acc[4] = {0,0,0,0};
    for (int i=0;i<32;i++){
      float wv = W1v[i*32+op];
      #pragma unroll
      for (int j=0;j<4;j++) acc[j] = fmaf(lv[jb+j][i*3+c], wv, acc[j]);
    }
    #pragma unroll
    for (int j=0;j<4;j++) v1[(size_t)(nb+jb+j)*96+f] = __float2half(acc[j]*0.17677669529663687f);
  }
  // sc_v
  #pragma unroll 1
  for (int f=q;f<96;f+=64){
    int op=f/3, c=f-3*op;
    float acc[4] = {0,0,0,0};
    for (int i=0;i<32;i++){
      const float* wp = Wscv + (i*4)*32 + op;
      float w0=wp[0], w1=wp[32], w2=wp[64], w3=wp[96];
      #pragma unroll
      for (int j=0;j<4;j++){
        float fold = laj[j][0]*w0 + laj[j][1]*w1 + laj[j][2]*w2 + laj[j][3]*w3;
        acc[j] = fmaf(lv[jb+j][i*3+c], fold, acc[j]);
      }
    }
    #pragma unroll
    for (int j=0;j<4;j++) scv[(size_t)(nb+jb+j)*96+f] = acc[j]*0.08838834764831845f;
  }
}

// ---------------- edge MLP: LDS-tiled, dot2 phases A/B + MFMA phase C ----------------
// R2 region uses padded row stride 196 (196%32=4 in f16x2 banks) so phase-C
// B-fragment loads are 2-way (free) instead of 4-way bank conflicts.
#define R2S 196
__launch_bounds__(256, 4)
__global__ void k_edgew(const float* __restrict__ dR, const int* __restrict__ perm,
                        const int* __restrict__ row, int n0, int n1, int cap,
                        const float* __restrict__ R0, const float* __restrict__ R1,
                        const float* __restrict__ R2,
                        __half* __restrict__ wbuf){
  __shared__ __align__(16) f16x2 hT2[32*64];   // 8 KB: [kpair][e]; first 2 KB (fp32 view) = rb staging
  __shared__ __align__(16) float r0s[512];     // 2 KB: R0 fp32
  __shared__ __align__(16) f16x2 wgt2[32*R2S]; // 24.5 KB: R1 pairs (2048, stride 64), then R2 (stride 196)
  int tid = threadIdx.x;
  int p0 = row[n0], p1 = row[n1];
  int vmax = p1 - p0; if (vmax > cap) vmax = cap;
  int tbase = blockIdx.x*64;
  if (tbase >= vmax) return;                    // wave-uniform early out
  int vcnt = vmax - tbase; if (vcnt > 64) vcnt = 64;

  // stage R0 (fp32) + R1 k-pairs (fp16)
  if (tid < 128) ((float4*)r0s)[tid] = ((const float4*)R0)[tid];
  for (int i=tid; i<2048; i+=256){
    int kp = i>>6, j = i&63;
    wgt2[i] = pack2f(R1[(2*kp)*64 + j], R1[(2*kp+1)*64 + j]);
  }
  // stage rb for the 64 edges into hT2 region (fp32 view, rows k<8)
  float* hTf = (float*)hT2;
  if (tid < 64){
    float rbv[8];
    if (tid < vcnt){
      int e = perm[p0 + tbase + tid];
      bessel8(dR, e, rbv);
    } else {
      #pragma unroll
      for (int k=0;k<8;k++) rbv[k]=0.0f;
    }
    #pragma unroll
    for (int k=0;k<8;k++) hTf[k*64 + tid] = rbv[k];
  }
  __syncthreads();

  int eg = tid & 15, e0 = eg*4;
  int jg = tid >> 4, j0 = jg*4;

  // read rb tile into regs (before overwriting hT2 with h1 pairs)
  float rb[8][4];
  {
    const float4* hTf4 = (const float4*)hTf;
    #pragma unroll
    for (int k=0;k<8;k++){
      float4 v = hTf4[k*16 + eg];
      rb[k][0]=v.x; rb[k][1]=v.y; rb[k][2]=v.z; rb[k][3]=v.w;
    }
  }
  // phase A: h1 tile (fp32 math, tiny K=8)
  float a[4][4];
  #pragma unroll
  for (int j=0;j<4;j++)
    #pragma unroll
    for (int e=0;e<4;e++) a[j][e]=0.0f;
  {
    const float4* r0s4 = (const float4*)r0s;
    #pragma unroll
    for (int k=0;k<8;k++){
      float4 w = r0s4[k*16 + jg];
      float wj[4] = {w.x,w.y,w.z,w.w};
      #pragma unroll
      for (int j=0;j<4;j++)
        #pragma unroll
        for (int e=0;e<4;e++) a[j][e] = fmaf(rb[k][e], wj[j], a[j][e]);
    }
  }
  #pragma unroll
  for (int j=0;j<4;j++)
    #pragma unroll
    for (int e=0;e<4;e++) a[j][e] = silu_f(a[j][e]*0.3535533905932738f);
  __syncthreads();   // all rb reads complete
  // write h1 as k-pairs: rows j0/2, j0/2+1 of hT2
  #pragma unroll
  for (int jp=0;jp<2;jp++){
    union {uint4 u; f16x2 h[4];} U;
    #pragma unroll
    for (int e=0;e<4;e++) U.h[e] = pack2f(a[2*jp][e], a[2*jp+1][e]);
    *(uint4*)(hT2 + (j0/2 + jp)*64 + e0) = U.u;
  }
  __syncthreads();

  // phase B: h2 tile via dot2 (K=64 -> 32 pairs)
  float b[4][4];
  #pragma unroll
  for (int j=0;j<4;j++)
    #pragma unroll
    for (int e=0;e<4;e++) b[j][e]=0.0f;
  #pragma unroll 4
  for (int kp=0; kp<32; kp++){
    union {uint4 u; f16x2 h[4];} H; H.u = *(const uint4*)(hT2 + kp*64 + e0);
    union {uint4 u; f16x2 h[4];} W; W.u = *(const uint4*)(wgt2 + kp*64 + j0);
    #pragma unroll
    for (int j=0;j<4;j++)
      #pragma unroll
      for (int e=0;e<4;e++) b[j][e] = dot2f(H.h[e], W.h[j], b[j][e]);
  }
  #pragma unroll
  for (int j=0;j<4;j++)
    #pragma unroll
    for (int e=0;e<4;e++) b[j][e] = silu_f(b[j][e]*0.125f);
  __syncthreads();   // all h1/wgt2(R1) reads complete
  #pragma unroll
  for (int jp=0;jp<2;jp++){
    union {uint4 u; f16x2 h[4];} U;
    #pragma unroll
    for (int e=0;e<4;e++) U.h[e] = pack2f(b[2*jp][e], b[2*jp+1][e]);
    *(uint4*)(hT2 + (j0/2 + jp)*64 + e0) = U.u;
  }
  // stage R2 k-pairs (overwrites R1 pair region; padded row stride R2S)
  for (int i=tid; i<6144; i+=256){
    int kp = i/192, o = i-192*kp;
    wgt2[kp*R2S + o] = pack2f(R2[(2*kp)*192 + o], R2[(2*kp+1)*192 + o]);
  }
  __syncthreads();

  // phase C via MFMA: wave wv handles edges [16*wv, 16*wv+16) of this 64-edge tile
  {
    int wv = tid >> 6;        // wave id 0..3
    int ln = tid & 63;
    int col = ln & 15;
    int quad = ln >> 4;
    const unsigned int* hT2u = (const unsigned int*)hT2;
    const unsigned int* wgt2u = (const unsigned int*)wgt2;
    int eA = 16*wv + col;     // A's m index
    union { uint4 u; f16x8 v; } A0, A1;
    A0.u.x = hT2u[(4*quad+0)*64 + eA];
    A0.u.y = hT2u[(4*quad+1)*64 + eA];
    A0.u.z = hT2u[(4*quad+2)*64 + eA];
    A0.u.w = hT2u[(4*quad+3)*64 + eA];
    A1.u.x = hT2u[(16+4*quad+0)*64 + eA];
    A1.u.y = hT2u[(16+4*quad+1)*64 + eA];
    A1.u.z = hT2u[(16+4*quad+2)*64 + eA];
    A1.u.w = hT2u[(16+4*quad+3)*64 + eA];
    int erow = 16*wv + 4*quad;           // D rows: erow+0..3
    #pragma unroll 1
    for (int ot=0; ot<12; ot++){
      int o = 16*ot + col;
      union { uint4 u; f16x8 v; } B0, B1;
      B0.u.x = wgt2u[(4*quad+0)*R2S + o];
      B0.u.y = wgt2u[(4*quad+1)*R2S + o];
      B0.u.z = wgt2u[(4*quad+2)*R2S + o];
      B0.u.w = wgt2u[(4*quad+3)*R2S + o];
      B1.u.x = wgt2u[(16+4*quad+0)*R2S + o];
      B1.u.y = wgt2u[(16+4*quad+1)*R2S + o];
      B1.u.z = wgt2u[(16+4*quad+2)*R2S + o];
      B1.u.w = wgt2u[(16+4*quad+3)*R2S + o];
      f32x4 acc = {0.0f,0.0f,0.0f,0.0f};
      acc = __builtin_amdgcn_mfma_f32_16x16x32_f16(A0.v, B0.v, acc, 0, 0, 0);
      acc = __builtin_amdgcn_mfma_f32_16x16x32_f16(A1.v, B1.v, acc, 0, 0, 0);
      #pragma unroll
      for (int r=0;r<4;r++){
        int eib = erow + r;
        if (eib < vcnt){
          int g = tbase + eib;
          wbuf[(size_t)g*192 + o] = __float2half(acc[r]);
        }
      }
    }
  }
}

// ---------------- gather: direct global reads (no wrow staging) ----------------
// Round-13 gather was still latency-bound (VALUBusy 37%): the wrow LDS stage
// added 2 serial sync phases but each wbuf byte is single-use. Direct reads
// (t<64 spans 128B contiguous per edge; other groups hit the same L1 lines)
// drop LDS to ~0.8 KB -> wave-cap occupancy, loads pipeline across j.
__launch_bounds__(384, 8)
__global__ void k_gather(const __half* __restrict__ wbuf, const int* __restrict__ perm,
                         const int* __restrict__ row, const int* __restrict__ senders,
                         const float* __restrict__ sh1,
                         const __half* __restrict__ s1, const __half* __restrict__ v1,
                         int n0, int cap,
                         float* __restrict__ a_s, float* __restrict__ a_v){
  __shared__ float sh1r[ECAP*3];
  __shared__ int   srcs[ECAP];
  int n = n0 + blockIdx.x;
  int t = threadIdx.x;
  int pc0 = row[n0];
  int p0 = row[n], p1 = row[n+1];
  int pmax = pc0 + cap; if (p1 > pmax) p1 = pmax;
  float acc = 0.0f;

  for (int base = p0; base < p1; base += ECAP){
    int bc = p1 - base; if (bc > ECAP) bc = ECAP;
    __syncthreads();   // protect LDS reuse across batches
    if (t < bc){
      int e = perm[base + t];
      srcs[t] = senders[e];
      sh1r[3*t+0] = sh1[3*e+0];
      sh1r[3*t+1] = sh1[3*e+1];
      sh1r[3*t+2] = sh1[3*e+2];
    }
    __syncthreads();
    const __half* wrow = wbuf + (size_t)(base - pc0)*192;
    if (t < 64){
      for (int j=0;j<bc;j++)
        acc = fmaf(__half2float(wrow[(size_t)j*192 + t]),
                   __half2float(s1[(size_t)srcs[j]*64 + t]), acc);
    } else if (t < 96){
      int i = t-64;
      for (int j=0;j<bc;j++){
        const __half* vr = v1 + (size_t)srcs[j]*96 + 3*i;
        float dv = __half2float(vr[0])*sh1r[j*3+0]
                 + __half2float(vr[1])*sh1r[j*3+1]
                 + __half2float(vr[2])*sh1r[j*3+2];
        acc = fmaf(__half2float(wrow[(size_t)j*192 + 160 + i]), dv, acc);
      }
    } else {
      int idx = t-96; int o = idx/3; int c = idx-3*o;
      if (o < 64){
        for (int j=0;j<bc;j++)
          acc = fmaf(__half2float(wrow[(size_t)j*192 + 64 + o]) *
                     __half2float(s1[(size_t)srcs[j]*64 + o]),
                     sh1r[j*3+c], acc);
      } else {
        int i = o-64;
        for (int j=0;j<bc;j++)
          acc = fmaf(__half2float(wrow[(size_t)j*192 + 128 + i]),
                     __half2float(v1[(size_t)srcs[j]*96 + 3*i + c]), acc);
      }
    }
  }

  if (t < 64){
    a_s[(size_t)n*96 + t] = 0.03125f*acc;                 // (1/8)*(1/sqrt(16))
  } else if (t < 96){
    a_s[(size_t)n*96 + t] = 0.018042195912175807f*acc;    // 0.03125/sqrt(3)
  } else {
    a_v[(size_t)n*288 + (t-96)] = 0.03125f*acc;
  }
}

// ---------------- fallback: atomic edge kernel (only if ws too small) ----------------
__device__ __forceinline__ void mlp_h2(const float* __restrict__ R0,
                                       const float* lR1, const float rb[8],
                                       float h2[64]){
  float h1[64];
  #pragma unroll
  for (int j=0;j<64;j+=4){
    float a0=0,a1=0,a2=0,a3=0;
    #pragma unroll
    for (int k=0;k<8;k++){
      float r = rb[k];
      const float* wp = R0 + k*64 + j;
      a0 = fmaf(r, wp[0], a0); a1 = fmaf(r, wp[1], a1);
      a2 = fmaf(r, wp[2], a2); a3 = fmaf(r, wp[3], a3);
    }
    h1[j+0]=silu_f(a0*0.3535533905932738f);
    h1[j+1]=silu_f(a1*0.3535533905932738f);
    h1[j+2]=silu_f(a2*0.3535533905932738f);
    h1[j+3]=silu_f(a3*0.3535533905932738f);
  }
  #pragma unroll
  for (int j=0;j<64;j+=4){
    float a0=0,a1=0,a2=0,a3=0;
    #pragma unroll
    for (int k=0;k<64;k++){
      float h = h1[k];
      float4 w4 = *(const float4*)(lR1 + k*64 + j);
      a0 = fmaf(h,w4.x,a0); a1 = fmaf(h,w4.y,a1);
      a2 = fmaf(h,w4.z,a2); a3 = fmaf(h,w4.w,a3);
    }
    h2[j+0]=silu_f(a0*0.125f);
    h2[j+1]=silu_f(a1*0.125f);
    h2[j+2]=silu_f(a2*0.125f);
    h2[j+3]=silu_f(a3*0.125f);
  }
}

__launch_bounds__(256, 2)
__global__ void k_edge(const float* __restrict__ dR, const float* __restrict__ sh1,
                       const int* __restrict__ senders, const int* __restrict__ receivers,
                       const __half* __restrict__ s1, const __half* __restrict__ v1,
                       const float* __restrict__ R0, const float* __restrict__ R1,
                       const float* __restrict__ R2,
                       float* __restrict__ a_s, float* __restrict__ a_v){
  __shared__ __align__(16) float lR1[64*64];
  __shared__ __align__(16) float lR2[64*192];
  int tid = threadIdx.x;
  for (int i=tid;i<4096;i+=256)  lR1[i]=R1[i];
  for (int i=tid;i<12288;i+=256) lR2[i]=R2[i];
  __syncthreads();
  int e = blockIdx.x*256 + tid;
  float rb[8];
  bessel8(dR, e, rb);
  float h2[64];
  mlp_h2(R0, lR1, rb, h2);
  int src = senders[e], dst = receivers[e];
  float sx=sh1[3*e+0], sy=sh1[3*e+1], sz=sh1[3*e+2];
  const __half* srow = s1 + (size_t)src*64;
  const __half* vrow = v1 + (size_t)src*96;
  float* asr = a_s + (size_t)dst*96;
  float* avr = a_v + (size_t)dst*288;
  #pragma unroll 1
  for (int o=0;o<64;o+=4){
    float w10=0,w11=0,w12=0,w13=0, w20=0,w21=0,w22=0,w23=0;
    #pragma unroll
    for (int k=0;k<64;k++){
      float h = h2[k];
      float4 wa = *(const float4*)(lR2 + k*192 + o);
      float4 wb = *(const float4*)(lR2 + k*192 + 64 + o);
      w10=fmaf(h,wa.x,w10); w11=fmaf(h,wa.y,w11); w12=fmaf(h,wa.z,w12); w13=fmaf(h,wa.w,w13);
      w20=fmaf(h,wb.x,w20); w21=fmaf(h,wb.y,w21); w22=fmaf(h,wb.z,w22); w23=fmaf(h,wb.w,w23);
    }
    float sev[4] = {__half2float(srow[o+0]), __half2float(srow[o+1]),
                    __half2float(srow[o+2]), __half2float(srow[o+3])};
    float w1a[4] = {w10,w11,w12,w13};
    float w2a[4] = {w20,w21,w22,w23};
    #pragma unroll
    for (int u=0;u<4;u++){
      atomicAdd(asr+o+u, 0.03125f*w1a[u]*sev[u]);
      float m = 0.03125f*w2a[u]*sev[u];
      atomicAdd(avr+(o+u)*3+0, m*sx);
      atomicAdd(avr+(o+u)*3+1, m*sy);
      atomicAdd(avr+(o+u)*3+2, m*sz);
    }
  }
  #pragma unroll 1
  for (int i0=0;i0<32;i0+=4){
    float w30=0,w31=0,w32=0,w33=0, w40=0,w41=0,w42=0,w43=0;
    #pragma unroll
    for (int k=0;k<64;k++){
      float h = h2[k];
      float4 wa = *(const float4*)(lR2 + k*192 + 128 + i0);
      float4 wb = *(const float4*)(lR2 + k*192 + 160 + i0);
      w30=fmaf(h,wa.x,w30); w31=fmaf(h,wa.y,w31); w32=fmaf(h,wa.z,w32); w33=fmaf(h,wa.w,w33);
      w40=fmaf(h,wb.x,w40); w41=fmaf(h,wb.y,w41); w42=fmaf(h,wb.z,w42); w43=fmaf(h,wb.w,w43);
    }
    float w3a[4] = {w30,w31,w32,w33};
    float w4a[4] = {w40,w41,w42,w43};
    #pragma unroll
    for (int u=0;u<4;u++){
      int i = i0+u;
      float vx=__half2float(vrow[3*i+0]), vy=__half2float(vrow[3*i+1]), vz=__half2float(vrow[3*i+2]);
      float dv = vx*sx + vy*sy + vz*sz;
      atomicAdd(asr+64+i, 0.018042195912175807f*w4a[u]*dv);
      float m3 = 0.03125f*w3a[u];
      atomicAdd(avr+(64+i)*3+0, m3*vx);
      atomicAdd(avr+(64+i)*3+1, m3*vy);
      atomicAdd(avr+(64+i)*3+2, m3*vz);
    }
  }
}

// ---------------- per-layer output transform: o_s, o_v, gating ----------------
__global__ void k_out(const float* __restrict__ a_s, const float* __restrict__ a_v,
                      const float* __restrict__ scs, const float* __restrict__ scv,
                      const float* __restrict__ W2s, const float* __restrict__ W2v,
                      float* __restrict__ s_out, float* __restrict__ v_out){
  __shared__ float las[2][96];
  __shared__ float lav[2][288];
  __shared__ float los[2][96];
  int tid = threadIdx.x;
  int j = tid>>7, t = tid&127;
  int n = blockIdx.x*2 + j;
  for (int i=t;i<96;i+=128)  las[j][i]=a_s[(size_t)n*96+i];
  for (int i=t;i<288;i+=128) lav[j][i]=a_v[(size_t)n*288+i];
  __syncthreads();
  if (t<96){
    float acc=0.0f;
    #pragma unroll 8
    for (int i=0;i<96;i++) acc += las[j][i]*W2s[i*96+t];
    los[j][t] = acc*0.10206207261596575f + scs[(size_t)n*96+t];
  }
  __syncthreads();
  if (t<64) s_out[(size_t)n*64+t] = silu_f(los[j][t]);
  if (t<96){
    int op=t/3, c=t-3*op;
    float acc=0.0f;
    #pragma unroll 8
    for (int i=0;i<96;i++) acc += lav[j][i*3+c]*W2v[i*32+op];
    float ov = acc*0.10206207261596575f + scv[(size_t)n*96+t];
    float g = silu_f(los[j][64+op]);
    v_out[(size_t)n*96+t] = ov*g;
  }
}

// ---------------- final heads: energy + mags ----------------
__global__ void k_final(const float* __restrict__ s, const float* __restrict__ nodes,
                        const int* __restrict__ n_node,
                        const float* __restrict__ Wen1, const float* __restrict__ Wen2,
                        const float* __restrict__ Wm1, const float* __restrict__ Wm2,
                        const float* __restrict__ scale_occ, const float* __restrict__ shift_occ,
                        const float* __restrict__ escale, const float* __restrict__ eshift,
                        float* __restrict__ out){
  __shared__ float eacc[NG];
  __shared__ int goff[NG+1];
  int tid = threadIdx.x;
  if (tid < NG) eacc[tid] = 0.0f;
  if (tid == 0){
    int c = 0; goff[0] = 0;
    for (int g=0; g<NG; g++){ c += n_node[g]; goff[g+1] = c; }
  }
  __syncthreads();
  int n = blockIdx.x*256 + tid;
  if (n < NN){
    float sv[64];
    #pragma unroll
    for (int i=0;i<64;i++) sv[i]=s[(size_t)n*64+i];
    float en=0.0f, m0=0.0f, m1=0.0f;
    #pragma unroll 1
    for (int jj=0;jj<32;jj++){
      float he=0.0f, hm=0.0f;
      #pragma unroll
      for (int i=0;i<64;i++){
        he = fmaf(sv[i], Wen1[i*32+jj], he);
        hm = fmaf(sv[i], Wm1[i*32+jj], hm);
      }
      he *= 0.125f; hm *= 0.125f;
      en = fmaf(he, Wen2[jj], en);
      m0 = fmaf(hm, Wm2[jj*2+0], m0);
      m1 = fmaf(hm, Wm2[jj*2+1], m1);
    }
    const float INVS32 = 0.17677669529663687f;
    en *= INVS32; m0 *= INVS32; m1 *= INVS32;
    en = escale[0]*en + eshift[0];
    int g = 0;
    for (int gg=0; gg<NG; gg++) if (n >= goff[gg+1]) g = gg+1;
    atomicAdd(&eacc[g], en);
    float nx=nodes[n*4+0], ny=nodes[n*4+1], nz=nodes[n*4+2];
    float sc0 = nx*scale_occ[0] + ny*scale_occ[2] + nz*scale_occ[4];
    float sc1 = nx*scale_occ[1] + ny*scale_occ[3] + nz*scale_occ[5];
    float sf0 = nx*shift_occ[0] + ny*shift_occ[2] + nz*shift_occ[4];
    float sf1 = nx*shift_occ[1] + ny*shift_occ[3] + nz*shift_occ[5];
    out[16 + n*2 + 0] = sc0*m0 + sf0;
    out[16 + n*2 + 1] = sc1*m1 + sf1;
  }
  __syncthreads();
  if (tid < NG) atomicAdd(&out[tid], eacc[tid]);
}

extern "C" void kernel_launch(void* const* d_in, const int* in_sizes, int n_in,
                              void* d_out, int out_size, void* d_ws, size_t ws_size,
                              hipStream_t stream){
  const float* nodes   = (const float*)d_in[0];
  const float* dR      = (const float*)d_in[1];
  const int*  senders  = (const int*)d_in[2];
  const int*  receivers= (const int*)d_in[3];
  const int*  n_node   = (const int*)d_in[4];
  const float* W_embed = (const float*)d_in[5];
  const float* W_sc_s  = (const float*)d_in[6];
  const float* W_sc_v  = (const float*)d_in[7];
  const float* W_l1_s  = (const float*)d_in[8];
  const float* W_l1_v  = (const float*)d_in[9];
  const float* Wr0     = (const float*)d_in[10];
  const float* Wr1     = (const float*)d_in[11];
  const float* Wr2     = (const float*)d_in[12];
  const float* W_l2_s  = (const float*)d_in[13];
  const float* W_l2_v  = (const float*)d_in[14];
  const float* W_en1   = (const float*)d_in[15];
  const float* W_en2   = (const float*)d_in[16];
  const float* W_mag1  = (const float*)d_in[17];
  const float* W_mag2  = (const float*)d_in[18];
  const float* scale_occ = (const float*)d_in[19];
  const float* shift_occ = (const float*)d_in[20];
  const float* escale  = (const float*)d_in[21];
  const float* eshift  = (const float*)d_in[22];
  float* out = (float*)d_out;
  float* ws  = (float*)d_ws;

  // ---- workspace map (float-index offsets; s1/v1/wbuf hold fp16 in-place) ----
  float*  sh1  = ws + 0;         // 960,000 f32
  float*  sA   = ws + 960000;    // 1,280,000 f32
  float*  vA   = ws + 2240000;   // 1,920,000 f32
  __half* s1h  = (__half*)(ws + 4160000);   // NN*64 halves (slot kept full-size)
  __half* v1h  = (__half*)(ws + 5440000);   // NN*96 halves
  float*  scs  = ws + 7360000;   // 1,920,000 f32
  float*  scv  = ws + 9280000;   // 1,920,000 f32
  float*  a_s  = ws + 11200000;  // 1,920,000 f32
  float*  a_v  = ws + 13120000;  // 5,760,000 f32 -> ends 18,880,000
  int*    cnt  = (int*)(ws + 18880000);  // 20,000
  int*    row  = (int*)(ws + 18900000);  // 20,001
  int*    cur  = (int*)(ws + 18920004);  // 20,000
  int*    perm = (int*)(ws + 18940004);  // 320,000 -> ends 19,260,004
  __half* wbuf = (__half*)(ws + 19260008); // capacity-adaptive fp16, 16B-aligned

  size_t wsf = ws_size / 4;
  // fp16 wbuf: 192 halves = 384 B per edge
  size_t cap_edges = (wsf > 19260008) ? ((wsf - 19260008)*4) / 384 : 0;
  if (cap_edges > 128) cap_edges -= 64;   // slack for 64-edge tile granularity
  const bool fast = cap_edges >= 4096;
  int cap = (int)((cap_edges > (size_t)NE) ? (size_t)NE + 8192 : cap_edges);
  // nodes per chunk: expected edges = 16*npc = 0.8*cap  (>35 sigma margin)
  int npc = (int)(cap / 20); if (npc < 1) npc = 1; if (npc > NN) npc = NN;
  int nchunk = (NN + npc - 1) / npc;

  hipMemsetAsync(vA, 0, (size_t)NN*96*sizeof(float), stream);   // v starts at zero
  hipMemsetAsync(out, 0, 16*sizeof(float), stream);             // energy accumulators

  k_geom<<<1250, 256, 0, stream>>>(dR, sh1);
  k_embed<<<5000, 256, 0, stream>>>(nodes, W_embed, sA);

  if (fast){
    hipMemsetAsync(cnt, 0, NN*sizeof(int), stream);
    k_hist<<<1250, 256, 0, stream>>>(receivers, cnt);
    k_scan<<<1, 1024, 0, stream>>>(cnt, row, cur);
    k_scatter<<<1250, 256, 0, stream>>>(receivers, cur, perm);
  }

  for (int l=0; l<2; l++){
    k_node<<<1250, 256, 0, stream>>>(sA, vA, nodes,
                                     W_l1_s + l*4096, W_l1_v + l*1024,
                                     W_sc_s + l*24576, W_sc_v + l*4096,
                                     s1h, v1h, scs, scv);
    if (fast){
      for (int ck=0; ck<nchunk; ck++){
        int n0 = ck*npc;
        int n1 = n0 + npc; if (n1 > NN) n1 = NN;
        int cover = (n1-n0)*17 + 4096; if (cover > cap) cover = cap;
        k_edgew<<<(cover+63)/64, 256, 0, stream>>>(dR, perm, row, n0, n1, cap,
                                       Wr0 + l*512, Wr1 + l*4096, Wr2 + l*12288, wbuf);
        k_gather<<<n1-n0, 384, 0, stream>>>(wbuf, perm, row, senders, sh1, s1h, v1h,
                                            n0, cap, a_s, a_v);
      }
    } else {
      hipMemsetAsync(a_s, 0, (size_t)NN*384*sizeof(float), stream);  // a_s+a_v contiguous
      k_edge<<<1250, 256, 0, stream>>>(dR, sh1, senders, receivers, s1h, v1h,
                                       Wr0 + l*512, Wr1 + l*4096, Wr2 + l*12288,
                                       a_s, a_v);
    }
    // writes back into sA/vA (safe: k_out reads only a_s/a_v/scs/scv)
    k_out<<<10000, 256, 0, stream>>>(a_s, a_v, scs, scv,
                                     W_l2_s + l*9216, W_l2_v + l*3072,
                                     sA, vA);
  }
  k_final<<<79, 256, 0, stream>>>(sA, nodes, n_node, W_en1, W_en2, W_mag1, W_mag2,
                                  scale_occ, shift_occ, escale, eshift, out);
}

// Round 15
// 850.756 us; speedup vs baseline: 1.0308x; 1.0308x over previous
//
#include <hip/hip_runtime.h>
#include <hip/hip_fp16.h>
#include <math.h>

#define NN 20000
#define NE 320000
#define NG 16
#define ECAP 48   // edges staged per batch in k_gather (deg ~16+-4, max ~40)

typedef _Float16 f16x2 __attribute__((ext_vector_type(2)));
typedef _Float16 f16x8 __attribute__((ext_vector_type(8)));
typedef float    f32x4 __attribute__((ext_vector_type(4)));

__device__ __forceinline__ float dot2f(f16x2 a, f16x2 b, float c){
#if defined(__has_builtin)
#if __has_builtin(__builtin_amdgcn_fdot2)
  return __builtin_amdgcn_fdot2(a, b, c, false);
#else
  return c + (float)a.x*(float)b.x + (float)a.y*(float)b.y;
#endif
#else
  return c + (float)a.x*(float)b.x + (float)a.y*(float)b.y;
#endif
}

__device__ __forceinline__ f16x2 pack2f(float a, float b){
  f16x2 r; r.x = (_Float16)a; r.y = (_Float16)b; return r;
}

__device__ __forceinline__ float silu_f(float x){ return x / (1.0f + __expf(-x)); }

// recompute bessel basis from dR (identical math/constants throughout all rounds)
__device__ __forceinline__ void bessel8(const float* __restrict__ dR, int e, float* rb){
  float x = dR[3*e+0], y = dR[3*e+1], z = dR[3*e+2];
  float r = sqrtf(x*x + y*y + z*z);
  float rs = fmaxf(r, 1e-6f);
  float inv = 1.0f / rs;
  float env;
  if (r < 3.5f) env = 1.0f;
  else if (r > 4.0f) env = 0.0f;
  else {
    float t = (r - 3.5f) * 2.0f;
    env = 0.5f * (cosf(3.14159265358979323846f * t) + 1.0f);
  }
  float c = 0.7071067811865476f * inv * env;
  #pragma unroll
  for (int k=0;k<8;k++){
    float arg = (float)(k+1) * 0.7853981633974483f * rs;
    rb[k] = c * sinf(arg);
  }
}

// ---------------- geometry: spherical harmonics only ----------------
__global__ void k_geom(const float* __restrict__ dR, float* __restrict__ sh1){
  int e = blockIdx.x*256 + threadIdx.x;
  if (e >= NE) return;
  float x = dR[3*e+0], y = dR[3*e+1], z = dR[3*e+2];
  float r = sqrtf(x*x + y*y + z*z);
  float inv = 1.0f / fmaxf(r, 1e-6f);
  const float SQ3 = 1.7320508075688772f;
  sh1[3*e+0] = SQ3 * x * inv;
  sh1[3*e+1] = SQ3 * y * inv;
  sh1[3*e+2] = SQ3 * z * inv;
}

// ---------------- node embedding ----------------
__global__ void k_embed(const float* __restrict__ nodes, const float* __restrict__ W,
                        float* __restrict__ s){
  int idx = blockIdx.x*256 + threadIdx.x;   // N*64 exact
  int n = idx>>6, o = idx&63;
  float a = nodes[n*4+0]*W[o] + nodes[n*4+1]*W[64+o]
          + nodes[n*4+2]*W[128+o] + nodes[n*4+3]*W[192+o];
  s[idx] = 0.5f*a;
}

// ---------------- counting sort of edges by receiver ----------------
__global__ void k_hist(const int* __restrict__ receivers, int* __restrict__ cnt){
  int e = blockIdx.x*256 + threadIdx.x;
  if (e < NE) atomicAdd(&cnt[receivers[e]], 1);
}

__global__ void k_scan(const int* __restrict__ cnt, int* __restrict__ row, int* __restrict__ cur){
  __shared__ int lsum[1024];
  int t = threadIdx.x;
  int base = t*20;
  int local[20];
  int s = 0;
  #pragma unroll
  for (int i=0;i<20;i++){
    int idx = base+i;
    int v = (idx<NN) ? cnt[idx] : 0;
    local[i] = s; s += v;
  }
  lsum[t] = s; __syncthreads();
  for (int off=1; off<1024; off<<=1){
    int v = (t>=off) ? lsum[t-off] : 0;
    __syncthreads();
    lsum[t] += v;
    __syncthreads();
  }
  int pre = (t>0) ? lsum[t-1] : 0;
  #pragma unroll
  for (int i=0;i<20;i++){
    int idx = base+i;
    if (idx<NN){ int r = pre+local[i]; row[idx]=r; cur[idx]=r; }
  }
  if (t==1023) row[NN] = lsum[1023];
}

__global__ void k_scatter(const int* __restrict__ receivers, int* __restrict__ cur,
                          int* __restrict__ perm){
  int e = blockIdx.x*256 + threadIdx.x;
  if (e < NE){
    int d = receivers[e];
    int p = atomicAdd(&cur[d], 1);
    perm[p] = e;
  }
}

// ---------------- per-layer node linears: 16 nodes/block, 4 nodes/wave ----------------
__global__ void k_node(const float* __restrict__ s, const float* __restrict__ v,
                       const float* __restrict__ attrs,
                       const float* __restrict__ W1s, const float* __restrict__ W1v,
                       const float* __restrict__ Wscs, const float* __restrict__ Wscv,
                       __half* __restrict__ s1, __half* __restrict__ v1,
                       float* __restrict__ scs, float* __restrict__ scv){
  __shared__ float ls[16][64];
  __shared__ float lv[16][96];
  __shared__ float la[16][4];
  int tid = threadIdx.x;
  int nb = blockIdx.x*16;   // 1250*16 = 20000 exact
  for (int i=tid;i<1024;i+=256) ls[i>>6][i&63] = s[(size_t)(nb+(i>>6))*64 + (i&63)];
  for (int i=tid;i<1536;i+=256){ int j=i/96, q=i-96*j; lv[j][q] = v[(size_t)(nb+j)*96+q]; }
  if (tid<64) la[tid>>2][tid&3] = attrs[(nb+(tid>>2))*4 + (tid&3)];
  __syncthreads();
  int w = tid>>6, q = tid&63;
  int jb = w*4;                       // this wave's 4 nodes: nb+jb .. nb+jb+3
  float laj[4][4];
  #pragma unroll
  for (int j=0;j<4;j++)
    #pragma unroll
    for (int e=0;e<4;e++) laj[j][e] = la[jb+j][e];

  // s1 = s @ W1s / 8
  {
    float acc[4] = {0,0,0,0};
    for (int i=0;i<64;i++){
      float wv = W1s[i*64+q];
      #pragma unroll
      for (int j=0;j<4;j++) acc[j] = fmaf(ls[jb+j][i], wv, acc[j]);
    }
    #pragma unroll
    for (int j=0;j<4;j++) s1[(size_t)(nb+jb+j)*64+q] = __float2half(acc[j]*0.125f);
  }
  // sc_s
  #pragma unroll 1
  for (int o=q;o<96;o+=64){
    float acc[4] = {0,0,0,0};
    for (int i=0;i<64;i++){
      const float* wp = Wscs + (i*4)*96 + o;
      float w0=wp[0], w1=wp[96], w2=wp[192], w3=wp[288];
      #pragma unroll
      for (int j=0;j<4;j++){
        float fold = laj[j][0]*w0 + laj[j][1]*w1 + laj[j][2]*w2 + laj[j][3]*w3;
        acc[j] = fmaf(ls[jb+j][i], fold, acc[j]);
      }
    }
    #pragma unroll
    for (int j=0;j<4;j++) scs[(size_t)(nb+jb+j)*96+o] = acc[j]*0.0625f;
  }
  // v1
  #pragma unroll 1
  for (int f=q;f<96;f+=64){
    int op=f/3, c=f-3*op;
    float acc[4] = {0,0,0,0};
    for (int i=0;i<32;i++){
      float wv = W1v[i*32+op];
      #pragma unroll
      for (int j=0;j<4;j++) acc[j] = fmaf(lv[jb+j][i*3+c], wv, acc[j]);
    }
    #pragma unroll
    for (int j=0;j<4;j++) v1[(size_t)(nb+jb+j)*96+f] = __float2half(acc[j]*0.17677669529663687f);
  }
  // sc_v
  #pragma unroll 1
  for (int f=q;f<96;f+=64){
    int op=f/3, c=f-3*op;
    float acc[4] = {0,0,0,0};
    for (int i=0;i<32;i++){
      const float* wp = Wscv + (i*4)*32 + op;
      float w0=wp[0], w1=wp[32], w2=wp[64], w3=wp[96];
      #pragma unroll
      for (int j=0;j<4;j++){
        float fold = laj[j][0]*w0 + laj[j][1]*w1 + laj[j][2]*w2 + laj[j][3]*w3;
        acc[j] = fmaf(lv[jb+j][i*3+c], fold, acc[j]);
      }
    }
    #pragma unroll
    for (int j=0;j<4;j++) scv[(size_t)(nb+jb+j)*96+f] = acc[j]*0.08838834764831845f;
  }
}

// ---------------- edge MLP: LDS-tiled, dot2 phases A/B + MFMA phase C ----------------
// R2 region uses padded row stride 196 (4-way -> free 2-way conflicts: round-14
// measured SQ_LDS_BANK_CONFLICT 3.4M -> 0.26M).
#define R2S 196
__launch_bounds__(256, 4)
__global__ void k_edgew(const float* __restrict__ dR, const int* __restrict__ perm,
                        const int* __restrict__ row, int n0, int n1, int cap,
                        const float* __restrict__ R0, const float* __restrict__ R1,
                        const float* __restrict__ R2,
                        __half* __restrict__ wbuf){
  __shared__ __align__(16) f16x2 hT2[32*64];   // 8 KB: [kpair][e]; first 2 KB (fp32 view) = rb staging
  __shared__ __align__(16) float r0s[512];     // 2 KB: R0 fp32
  __shared__ __align__(16) f16x2 wgt2[32*R2S]; // 24.5 KB: R1 pairs (stride 64), then R2 (stride 196)
  int tid = threadIdx.x;
  int p0 = row[n0], p1 = row[n1];
  int vmax = p1 - p0; if (vmax > cap) vmax = cap;
  int tbase = blockIdx.x*64;
  if (tbase >= vmax) return;                    // wave-uniform early out
  int vcnt = vmax - tbase; if (vcnt > 64) vcnt = 64;

  // stage R0 (fp32) + R1 k-pairs (fp16)
  if (tid < 128) ((float4*)r0s)[tid] = ((const float4*)R0)[tid];
  for (int i=tid; i<2048; i+=256){
    int kp = i>>6, j = i&63;
    wgt2[i] = pack2f(R1[(2*kp)*64 + j], R1[(2*kp+1)*64 + j]);
  }
  // stage rb for the 64 edges into hT2 region (fp32 view, rows k<8)
  float* hTf = (float*)hT2;
  if (tid < 64){
    float rbv[8];
    if (tid < vcnt){
      int e = perm[p0 + tbase + tid];
      bessel8(dR, e, rbv);
    } else {
      #pragma unroll
      for (int k=0;k<8;k++) rbv[k]=0.0f;
    }
    #pragma unroll
    for (int k=0;k<8;k++) hTf[k*64 + tid] = rbv[k];
  }
  __syncthreads();

  int eg = tid & 15, e0 = eg*4;
  int jg = tid >> 4, j0 = jg*4;

  // read rb tile into regs (before overwriting hT2 with h1 pairs)
  float rb[8][4];
  {
    const float4* hTf4 = (const float4*)hTf;
    #pragma unroll
    for (int k=0;k<8;k++){
      float4 v = hTf4[k*16 + eg];
      rb[k][0]=v.x; rb[k][1]=v.y; rb[k][2]=v.z; rb[k][3]=v.w;
    }
  }
  // phase A: h1 tile (fp32 math, tiny K=8)
  float a[4][4];
  #pragma unroll
  for (int j=0;j<4;j++)
    #pragma unroll
    for (int e=0;e<4;e++) a[j][e]=0.0f;
  {
    const float4* r0s4 = (const float4*)r0s;
    #pragma unroll
    for (int k=0;k<8;k++){
      float4 w = r0s4[k*16 + jg];
      float wj[4] = {w.x,w.y,w.z,w.w};
      #pragma unroll
      for (int j=0;j<4;j++)
        #pragma unroll
        for (int e=0;e<4;e++) a[j][e] = fmaf(rb[k][e], wj[j], a[j][e]);
    }
  }
  #pragma unroll
  for (int j=0;j<4;j++)
    #pragma unroll
    for (int e=0;e<4;e++) a[j][e] = silu_f(a[j][e]*0.3535533905932738f);
  __syncthreads();   // all rb reads complete
  // write h1 as k-pairs: rows j0/2, j0/2+1 of hT2
  #pragma unroll
  for (int jp=0;jp<2;jp++){
    union {uint4 u; f16x2 h[4];} U;
    #pragma unroll
    for (int e=0;e<4;e++) U.h[e] = pack2f(a[2*jp][e], a[2*jp+1][e]);
    *(uint4*)(hT2 + (j0/2 + jp)*64 + e0) = U.u;
  }
  __syncthreads();

  // phase B: h2 tile via dot2 (K=64 -> 32 pairs)
  float b[4][4];
  #pragma unroll
  for (int j=0;j<4;j++)
    #pragma unroll
    for (int e=0;e<4;e++) b[j][e]=0.0f;
  #pragma unroll 4
  for (int kp=0; kp<32; kp++){
    union {uint4 u; f16x2 h[4];} H; H.u = *(const uint4*)(hT2 + kp*64 + e0);
    union {uint4 u; f16x2 h[4];} W; W.u = *(const uint4*)(wgt2 + kp*64 + j0);
    #pragma unroll
    for (int j=0;j<4;j++)
      #pragma unroll
      for (int e=0;e<4;e++) b[j][e] = dot2f(H.h[e], W.h[j], b[j][e]);
  }
  #pragma unroll
  for (int j=0;j<4;j++)
    #pragma unroll
    for (int e=0;e<4;e++) b[j][e] = silu_f(b[j][e]*0.125f);
  __syncthreads();   // all h1/wgt2(R1) reads complete
  #pragma unroll
  for (int jp=0;jp<2;jp++){
    union {uint4 u; f16x2 h[4];} U;
    #pragma unroll
    for (int e=0;e<4;e++) U.h[e] = pack2f(b[2*jp][e], b[2*jp+1][e]);
    *(uint4*)(hT2 + (j0/2 + jp)*64 + e0) = U.u;
  }
  // stage R2 k-pairs (overwrites R1 pair region; padded row stride R2S)
  for (int i=tid; i<6144; i+=256){
    int kp = i/192, o = i-192*kp;
    wgt2[kp*R2S + o] = pack2f(R2[(2*kp)*192 + o], R2[(2*kp+1)*192 + o]);
  }
  __syncthreads();

  // phase C via MFMA: wave wv handles edges [16*wv, 16*wv+16) of this 64-edge tile
  {
    int wv = tid >> 6;        // wave id 0..3
    int ln = tid & 63;
    int col = ln & 15;
    int quad = ln >> 4;
    const unsigned int* hT2u = (const unsigned int*)hT2;
    const unsigned int* wgt2u = (const unsigned int*)wgt2;
    int eA = 16*wv + col;     // A's m index
    union { uint4 u; f16x8 v; } A0, A1;
    A0.u.x = hT2u[(4*quad+0)*64 + eA];
    A0.u.y = hT2u[(4*quad+1)*64 + eA];
    A0.u.z = hT2u[(4*quad+2)*64 + eA];
    A0.u.w = hT2u[(4*quad+3)*64 + eA];
    A1.u.x = hT2u[(16+4*quad+0)*64 + eA];
    A1.u.y = hT2u[(16+4*quad+1)*64 + eA];
    A1.u.z = hT2u[(16+4*quad+2)*64 + eA];
    A1.u.w = hT2u[(16+4*quad+3)*64 + eA];
    int erow = 16*wv + 4*quad;           // D rows: erow+0..3
    #pragma unroll 1
    for (int ot=0; ot<12; ot++){
      int o = 16*ot + col;
      union { uint4 u; f16x8 v; } B0, B1;
      B0.u.x = wgt2u[(4*quad+0)*R2S + o];
      B0.u.y = wgt2u[(4*quad+1)*R2S + o];
      B0.u.z = wgt2u[(4*quad+2)*R2S + o];
      B0.u.w = wgt2u[(4*quad+3)*R2S + o];
      B1.u.x = wgt2u[(16+4*quad+0)*R2S + o];
      B1.u.y = wgt2u[(16+4*quad+1)*R2S + o];
      B1.u.z = wgt2u[(16+4*quad+2)*R2S + o];
      B1.u.w = wgt2u[(16+4*quad+3)*R2S + o];
      f32x4 acc = {0.0f,0.0f,0.0f,0.0f};
      acc = __builtin_amdgcn_mfma_f32_16x16x32_f16(A0.v, B0.v, acc, 0, 0, 0);
      acc = __builtin_amdgcn_mfma_f32_16x16x32_f16(A1.v, B1.v, acc, 0, 0, 0);
      #pragma unroll
      for (int r=0;r<4;r++){
        int eib = erow + r;
        if (eib < vcnt){
          int g = tbase + eib;
          wbuf[(size_t)g*192 + o] = __float2half(acc[r]);
        }
      }
    }
  }
}

// ---------------- gather, stage-then-compute (round-13 proven 85.5us):
// wrow staged via coalesced bursts (kills dependent-load latency chain);
// s1/v1 read direct from L2-resident tables. LDS ~19.3 KB.
__launch_bounds__(384, 8)
__global__ void k_gather(const __half* __restrict__ wbuf, const int* __restrict__ perm,
                         const int* __restrict__ row, const int* __restrict__ senders,
                         const float* __restrict__ sh1,
                         const __half* __restrict__ s1, const __half* __restrict__ v1,
                         int n0, int cap,
                         float* __restrict__ a_s, float* __restrict__ a_v){
  __shared__ __align__(16) __half wrow[ECAP*192];   // 18.4 KB
  __shared__ float sh1r[ECAP*3];
  __shared__ int   srcs[ECAP];
  int n = n0 + blockIdx.x;
  int t = threadIdx.x;
  int pc0 = row[n0];
  int p0 = row[n], p1 = row[n+1];
  int pmax = pc0 + cap; if (p1 > pmax) p1 = pmax;
  float acc = 0.0f;

  for (int base = p0; base < p1; base += ECAP){
    int bc = p1 - base; if (bc > ECAP) bc = ECAP;
    __syncthreads();   // protect LDS reuse across batches
    if (t < bc){
      int e = perm[base + t];
      srcs[t] = senders[e];
      sh1r[3*t+0] = sh1[3*e+0];
      sh1r[3*t+1] = sh1[3*e+1];
      sh1r[3*t+2] = sh1[3*e+2];
    }
    __syncthreads();
    {
      const uint4* wsrc = (const uint4*)(wbuf + (size_t)(base - pc0)*192); // 384B rows, contiguous
      uint4* wdst = (uint4*)wrow;
      int cnt = bc*24;                      // 24 uint4 per edge row
      for (int i=t; i<cnt; i+=384) wdst[i] = wsrc[i];
    }
    __syncthreads();
    if (t < 64){
      for (int j=0;j<bc;j++)
        acc = fmaf(__half2float(wrow[j*192 + t]),
                   __half2float(s1[(size_t)srcs[j]*64 + t]), acc);
    } else if (t < 96){
      int i = t-64;
      for (int j=0;j<bc;j++){
        const __half* vr = v1 + (size_t)srcs[j]*96 + 3*i;
        float dv = __half2float(vr[0])*sh1r[j*3+0]
                 + __half2float(vr[1])*sh1r[j*3+1]
                 + __half2float(vr[2])*sh1r[j*3+2];
        acc = fmaf(__half2float(wrow[j*192 + 160 + i]), dv, acc);
      }
    } else {
      int idx = t-96; int o = idx/3; int c = idx-3*o;
      if (o < 64){
        for (int j=0;j<bc;j++)
          acc = fmaf(__half2float(wrow[j*192 + 64 + o]) *
                     __half2float(s1[(size_t)srcs[j]*64 + o]),
                     sh1r[j*3+c], acc);
      } else {
        int i = o-64;
        for (int j=0;j<bc;j++)
          acc = fmaf(__half2float(wrow[j*192 + 128 + i]),
                     __half2float(v1[(size_t)srcs[j]*96 + 3*i + c]), acc);
      }
    }
  }

  if (t < 64){
    a_s[(size_t)n*96 + t] = 0.03125f*acc;                 // (1/8)*(1/sqrt(16))
  } else if (t < 96){
    a_s[(size_t)n*96 + t] = 0.018042195912175807f*acc;    // 0.03125/sqrt(3)
  } else {
    a_v[(size_t)n*288 + (t-96)] = 0.03125f*acc;
  }
}

// ---------------- fallback: atomic edge kernel (only if ws too small) ----------------
__device__ __forceinline__ void mlp_h2(const float* __restrict__ R0,
                                       const float* lR1, const float rb[8],
                                       float h2[64]){
  float h1[64];
  #pragma unroll
  for (int j=0;j<64;j+=4){
    float a0=0,a1=0,a2=0,a3=0;
    #pragma unroll
    for (int k=0;k<8;k++){
      float r = rb[k];
      const float* wp = R0 + k*64 + j;
      a0 = fmaf(r, wp[0], a0); a1 = fmaf(r, wp[1], a1);
      a2 = fmaf(r, wp[2], a2); a3 = fmaf(r, wp[3], a3);
    }
    h1[j+0]=silu_f(a0*0.3535533905932738f);
    h1[j+1]=silu_f(a1*0.3535533905932738f);
    h1[j+2]=silu_f(a2*0.3535533905932738f);
    h1[j+3]=silu_f(a3*0.3535533905932738f);
  }
  #pragma unroll
  for (int j=0;j<64;j+=4){
    float a0=0,a1=0,a2=0,a3=0;
    #pragma unroll
    for (int k=0;k<64;k++){
      float h = h1[k];
      float4 w4 = *(const float4*)(lR1 + k*64 + j);
      a0 = fmaf(h,w4.x,a0); a1 = fmaf(h,w4.y,a1);
      a2 = fmaf(h,w4.z,a2); a3 = fmaf(h,w4.w,a3);
    }
    h2[j+0]=silu_f(a0*0.125f);
    h2[j+1]=silu_f(a1*0.125f);
    h2[j+2]=silu_f(a2*0.125f);
    h2[j+3]=silu_f(a3*0.125f);
  }
}

__launch_bounds__(256, 2)
__global__ void k_edge(const float* __restrict__ dR, const float* __restrict__ sh1,
                       const int* __restrict__ senders, const int* __restrict__ receivers,
                       const __half* __restrict__ s1, const __half* __restrict__ v1,
                       const float* __restrict__ R0, const float* __restrict__ R1,
                       const float* __restrict__ R2,
                       float* __restrict__ a_s, float* __restrict__ a_v){
  __shared__ __align__(16) float lR1[64*64];
  __shared__ __align__(16) float lR2[64*192];
  int tid = threadIdx.x;
  for (int i=tid;i<4096;i+=256)  lR1[i]=R1[i];
  for (int i=tid;i<12288;i+=256) lR2[i]=R2[i];
  __syncthreads();
  int e = blockIdx.x*256 + tid;
  float rb[8];
  bessel8(dR, e, rb);
  float h2[64];
  mlp_h2(R0, lR1, rb, h2);
  int src = senders[e], dst = receivers[e];
  float sx=sh1[3*e+0], sy=sh1[3*e+1], sz=sh1[3*e+2];
  const __half* srow = s1 + (size_t)src*64;
  const __half* vrow = v1 + (size_t)src*96;
  float* asr = a_s + (size_t)dst*96;
  float* avr = a_v + (size_t)dst*288;
  #pragma unroll 1
  for (int o=0;o<64;o+=4){
    float w10=0,w11=0,w12=0,w13=0, w20=0,w21=0,w22=0,w23=0;
    #pragma unroll
    for (int k=0;k<64;k++){
      float h = h2[k];
      float4 wa = *(const float4*)(lR2 + k*192 + o);
      float4 wb = *(const float4*)(lR2 + k*192 + 64 + o);
      w10=fmaf(h,wa.x,w10); w11=fmaf(h,wa.y,w11); w12=fmaf(h,wa.z,w12); w13=fmaf(h,wa.w,w13);
      w20=fmaf(h,wb.x,w20); w21=fmaf(h,wb.y,w21); w22=fmaf(h,wb.z,w22); w23=fmaf(h,wb.w,w23);
    }
    float sev[4] = {__half2float(srow[o+0]), __half2float(srow[o+1]),
                    __half2float(srow[o+2]), __half2float(srow[o+3])};
    float w1a[4] = {w10,w11,w12,w13};
    float w2a[4] = {w20,w21,w22,w23};
    #pragma unroll
    for (int u=0;u<4;u++){
      atomicAdd(asr+o+u, 0.03125f*w1a[u]*sev[u]);
      float m = 0.03125f*w2a[u]*sev[u];
      atomicAdd(avr+(o+u)*3+0, m*sx);
      atomicAdd(avr+(o+u)*3+1, m*sy);
      atomicAdd(avr+(o+u)*3+2, m*sz);
    }
  }
  #pragma unroll 1
  for (int i0=0;i0<32;i0+=4){
    float w30=0,w31=0,w32=0,w33=0, w40=0,w41=0,w42=0,w43=0;
    #pragma unroll
    for (int k=0;k<64;k++){
      float h = h2[k];
      float4 wa = *(const float4*)(lR2 + k*192 + 128 + i0);
      float4 wb = *(const float4*)(lR2 + k*192 + 160 + i0);
      w30=fmaf(h,wa.x,w30); w31=fmaf(h,wa.y,w31); w32=fmaf(h,wa.z,w32); w33=fmaf(h,wa.w,w33);
      w40=fmaf(h,wb.x,w40); w41=fmaf(h,wb.y,w41); w42=fmaf(h,wb.z,w42); w43=fmaf(h,wb.w,w43);
    }
    float w3a[4] = {w30,w31,w32,w33};
    float w4a[4] = {w40,w41,w42,w43};
    #pragma unroll
    for (int u=0;u<4;u++){
      int i = i0+u;
      float vx=__half2float(vrow[3*i+0]), vy=__half2float(vrow[3*i+1]), vz=__half2float(vrow[3*i+2]);
      float dv = vx*sx + vy*sy + vz*sz;
      atomicAdd(asr+64+i, 0.018042195912175807f*w4a[u]*dv);
      float m3 = 0.03125f*w3a[u];
      atomicAdd(avr+(64+i)*3+0, m3*vx);
      atomicAdd(avr+(64+i)*3+1, m3*vy);
      atomicAdd(avr+(64+i)*3+2, m3*vz);
    }
  }
}

// ---------------- per-layer output transform: o_s, o_v, gating ----------------
__global__ void k_out(const float* __restrict__ a_s, const float* __restrict__ a_v,
                      const float* __restrict__ scs, const float* __restrict__ scv,
                      const float* __restrict__ W2s, const float* __restrict__ W2v,
                      float* __restrict__ s_out, float* __restrict__ v_out){
  __shared__ float las[2][96];
  __shared__ float lav[2][288];
  __shared__ float los[2][96];
  int tid = threadIdx.x;
  int j = tid>>7, t = tid&127;
  int n = blockIdx.x*2 + j;
  for (int i=t;i<96;i+=128)  las[j][i]=a_s[(size_t)n*96+i];
  for (int i=t;i<288;i+=128) lav[j][i]=a_v[(size_t)n*288+i];
  __syncthreads();
  if (t<96){
    float acc=0.0f;
    #pragma unroll 8
    for (int i=0;i<96;i++) acc += las[j][i]*W2s[i*96+t];
    los[j][t] = acc*0.10206207261596575f + scs[(size_t)n*96+t];
  }
  __syncthreads();
  if (t<64) s_out[(size_t)n*64+t] = silu_f(los[j][t]);
  if (t<96){
    int op=t/3, c=t-3*op;
    float acc=0.0f;
    #pragma unroll 8
    for (int i=0;i<96;i++) acc += lav[j][i*3+c]*W2v[i*32+op];
    float ov = acc*0.10206207261596575f + scv[(size_t)n*96+t];
    float g = silu_f(los[j][64+op]);
    v_out[(size_t)n*96+t] = ov*g;
  }
}

// ---------------- final heads: energy + mags ----------------
__global__ void k_final(const float* __restrict__ s, const float* __restrict__ nodes,
                        const int* __restrict__ n_node,
                        const float* __restrict__ Wen1, const float* __restrict__ Wen2,
                        const float* __restrict__ Wm1, const float* __restrict__ Wm2,
                        const float* __restrict__ scale_occ, const float* __restrict__ shift_occ,
                        const float* __restrict__ escale, const float* __restrict__ eshift,
                        float* __restrict__ out){
  __shared__ float eacc[NG];
  __shared__ int goff[NG+1];
  int tid = threadIdx.x;
  if (tid < NG) eacc[tid] = 0.0f;
  if (tid == 0){
    int c = 0; goff[0] = 0;
    for (int g=0; g<NG; g++){ c += n_node[g]; goff[g+1] = c; }
  }
  __syncthreads();
  int n = blockIdx.x*256 + tid;
  if (n < NN){
    float sv[64];
    #pragma unroll
    for (int i=0;i<64;i++) sv[i]=s[(size_t)n*64+i];
    float en=0.0f, m0=0.0f, m1=0.0f;
    #pragma unroll 1
    for (int jj=0;jj<32;jj++){
      float he=0.0f, hm=0.0f;
      #pragma unroll
      for (int i=0;i<64;i++){
        he = fmaf(sv[i], Wen1[i*32+jj], he);
        hm = fmaf(sv[i], Wm1[i*32+jj], hm);
      }
      he *= 0.125f; hm *= 0.125f;
      en = fmaf(he, Wen2[jj], en);
      m0 = fmaf(hm, Wm2[jj*2+0], m0);
      m1 = fmaf(hm, Wm2[jj*2+1], m1);
    }
    const float INVS32 = 0.17677669529663687f;
    en *= INVS32; m0 *= INVS32; m1 *= INVS32;
    en = escale[0]*en + eshift[0];
    int g = 0;
    for (int gg=0; gg<NG; gg++) if (n >= goff[gg+1]) g = gg+1;
    atomicAdd(&eacc[g], en);
    float nx=nodes[n*4+0], ny=nodes[n*4+1], nz=nodes[n*4+2];
    float sc0 = nx*scale_occ[0] + ny*scale_occ[2] + nz*scale_occ[4];
    float sc1 = nx*scale_occ[1] + ny*scale_occ[3] + nz*scale_occ[5];
    float sf0 = nx*shift_occ[0] + ny*shift_occ[2] + nz*shift_occ[4];
    float sf1 = nx*shift_occ[1] + ny*shift_occ[3] + nz*shift_occ[5];
    out[16 + n*2 + 0] = sc0*m0 + sf0;
    out[16 + n*2 + 1] = sc1*m1 + sf1;
  }
  __syncthreads();
  if (tid < NG) atomicAdd(&out[tid], eacc[tid]);
}

extern "C" void kernel_launch(void* const* d_in, const int* in_sizes, int n_in,
                              void* d_out, int out_size, void* d_ws, size_t ws_size,
                              hipStream_t stream){
  const float* nodes   = (const float*)d_in[0];
  const float* dR      = (const float*)d_in[1];
  const int*  senders  = (const int*)d_in[2];
  const int*  receivers= (const int*)d_in[3];
  const int*  n_node   = (const int*)d_in[4];
  const float* W_embed = (const float*)d_in[5];
  const float* W_sc_s  = (const float*)d_in[6];
  const float* W_sc_v  = (const float*)d_in[7];
  const float* W_l1_s  = (const float*)d_in[8];
  const float* W_l1_v  = (const float*)d_in[9];
  const float* Wr0     = (const float*)d_in[10];
  const float* Wr1     = (const float*)d_in[11];
  const float* Wr2     = (const float*)d_in[12];
  const float* W_l2_s  = (const float*)d_in[13];
  const float* W_l2_v  = (const float*)d_in[14];
  const float* W_en1   = (const float*)d_in[15];
  const float* W_en2   = (const float*)d_in[16];
  const float* W_mag1  = (const float*)d_in[17];
  const float* W_mag2  = (const float*)d_in[18];
  const float* scale_occ = (const float*)d_in[19];
  const float* shift_occ = (const float*)d_in[20];
  const float* escale  = (const float*)d_in[21];
  const float* eshift  = (const float*)d_in[22];
  float* out = (float*)d_out;
  float* ws  = (float*)d_ws;

  // ---- workspace map (float-index offsets; s1/v1/wbuf hold fp16 in-place) ----
  float*  sh1  = ws + 0;         // 960,000 f32
  float*  sA   = ws + 960000;    // 1,280,000 f32
  float*  vA   = ws + 2240000;   // 1,920,000 f32
  __half* s1h  = (__half*)(ws + 4160000);   // NN*64 halves (slot kept full-size)
  __half* v1h  = (__half*)(ws + 5440000);   // NN*96 halves
  float*  scs  = ws + 7360000;   // 1,920,000 f32
  float*  scv  = ws + 9280000;   // 1,920,000 f32
  float*  a_s  = ws + 11200000;  // 1,920,000 f32
  float*  a_v  = ws + 13120000;  // 5,760,000 f32 -> ends 18,880,000
  int*    cnt  = (int*)(ws + 18880000);  // 20,000
  int*    row  = (int*)(ws + 18900000);  // 20,001
  int*    cur  = (int*)(ws + 18920004);  // 20,000
  int*    perm = (int*)(ws + 18940004);  // 320,000 -> ends 19,260,004
  __half* wbuf = (__half*)(ws + 19260008); // capacity-adaptive fp16, 16B-aligned

  size_t wsf = ws_size / 4;
  // fp16 wbuf: 192 halves = 384 B per edge
  size_t cap_edges = (wsf > 19260008) ? ((wsf - 19260008)*4) / 384 : 0;
  if (cap_edges > 128) cap_edges -= 64;   // slack for 64-edge tile granularity
  const bool fast = cap_edges >= 4096;
  int cap = (int)((cap_edges > (size_t)NE) ? (size_t)NE + 8192 : cap_edges);
  // nodes per chunk: expected edges = 16*npc = 0.8*cap  (>35 sigma margin)
  int npc = (int)(cap / 20); if (npc < 1) npc = 1; if (npc > NN) npc = NN;
  int nchunk = (NN + npc - 1) / npc;

  hipMemsetAsync(vA, 0, (size_t)NN*96*sizeof(float), stream);   // v starts at zero
  hipMemsetAsync(out, 0, 16*sizeof(float), stream);             // energy accumulators

  k_geom<<<1250, 256, 0, stream>>>(dR, sh1);
  k_embed<<<5000, 256, 0, stream>>>(nodes, W_embed, sA);

  if (fast){
    hipMemsetAsync(cnt, 0, NN*sizeof(int), stream);
    k_hist<<<1250, 256, 0, stream>>>(receivers, cnt);
    k_scan<<<1, 1024, 0, stream>>>(cnt, row, cur);
    k_scatter<<<1250, 256, 0, stream>>>(receivers, cur, perm);
  }

  for (int l=0; l<2; l++){
    k_node<<<1250, 256, 0, stream>>>(sA, vA, nodes,
                                     W_l1_s + l*4096, W_l1_v + l*1024,
                                     W_sc_s + l*24576, W_sc_v + l*4096,
                                     s1h, v1h, scs, scv);
    if (fast){
      for (int ck=0; ck<nchunk; ck++){
        int n0 = ck*npc;
        int n1 = n0 + npc; if (n1 > NN) n1 = NN;
        int cover = (n1-n0)*17 + 4096; if (cover > cap) cover = cap;
        k_edgew<<<(cover+63)/64, 256, 0, stream>>>(dR, perm, row, n0, n1, cap,
                                       Wr0 + l*512, Wr1 + l*4096, Wr2 + l*12288, wbuf);
        k_gather<<<n1-n0, 384, 0, stream>>>(wbuf, perm, row, senders, sh1, s1h, v1h,
                                            n0, cap, a_s, a_v);
      }
    } else {
      hipMemsetAsync(a_s, 0, (size_t)NN*384*sizeof(float), stream);  // a_s+a_v contiguous
      k_edge<<<1250, 256, 0, stream>>>(dR, sh1, senders, receivers, s1h, v1h,
                                       Wr0 + l*512, Wr1 + l*4096, Wr2 + l*12288,
                                       a_s, a_v);
    }
    // writes back into sA/vA (safe: k_out reads only a_s/a_v/scs/scv)
    k_out<<<10000, 256, 0, stream>>>(a_s, a_v, scs, scv,
                                     W_l2_s + l*9216, W_l2_v + l*3072,
                                     sA, vA);
  }
  k_final<<<79, 256, 0, stream>>>(sA, nodes, n_node, W_en1, W_en2, W_mag1, W_mag2,
                                  scale_occ, shift_occ, escale, eshift, out);
}